// Round 9
// baseline (374.073 us; speedup 1.0000x reference)
//
#include <hip/hip_runtime.h>

#define NUM_B 8
#define NUM_C 64
#define NUM_O 64
#define DIM_H 256
#define DIM_W 256
#define SEG   8           // 8 output rows per block
#define WT    128         // w-tile per block -> grid 512 = 2 blocks/CU
#define TPB   512
#define XSS   72          // xs row stride in bf16 elems: 144 B

typedef __attribute__((ext_vector_type(8))) short bf16x8;
typedef __attribute__((ext_vector_type(4))) float f32x4;

__device__ __forceinline__ unsigned bf16r(float f) {   // RTNE fp32 -> bf16 bits
    unsigned u = __float_as_uint(f);
    return (u + 0x7fffu + ((u >> 16) & 1u)) >> 16;
}
__device__ __forceinline__ unsigned cvt_pk_bf16(float lo, float hi) {
    unsigned r;
    asm("v_cvt_pk_bf16_f32 %0, %1, %2" : "=v"(r) : "v"(lo), "v"(hi));
    return r;
}

__global__ __launch_bounds__(TPB, 4)   // round-6 proven config: VGPR 64, 2 blocks/CU, no spill
void cpd_mfma(const float* __restrict__ x, const float* __restrict__ w1,
              const float* __restrict__ wh, const float* __restrict__ wv,
              const float* __restrict__ bias, float* __restrict__ out)
{
    // DOUBLE-buffered transposed x-row slice: xs[wl+1][c] bf16; rows 0 / WT+1 = halo columns.
    // Iter HH: pack row (h0+HH) -> xs(HH&1)  WHILE  GEMM row (h0+HH-1) <- xs((HH-1)&1).
    __shared__ unsigned short xs0[WT + 2][XSS];
    __shared__ unsigned short xs1[WT + 2][XSS];
    __shared__ float wvb[NUM_O][4];    // {wv0, wv1, wv2, bias} per o

    const int tid  = threadIdx.x;
    const int lane = tid & 63;
    const int wave = tid >> 6;         // [0,8)
    const int l15  = lane & 15;
    const int lhi  = lane >> 4;
    const int bx   = blockIdx.x;
    const int w0   = (bx & 1) * WT;
    const int h0   = ((bx >> 1) & 31) * SEG;
    const int b    = bx >> 6;

    const int ot = wave & 3;           // o-tile: o = ot*16 ..
    const int wq = wave >> 2;          // w-half of tile [0,2): wl = wq*64 ..

    // ---- A fragments (regs): A_s[o][c] = wh[o][s] * w1[o][c]; slot: m=o=l15, k=c=kb*32+lhi*8+i
    bf16x8 afrag[3][2];
    {
        const int o = ot * 16 + l15;
        const float a0 = wh[o*3+0], a1 = wh[o*3+1], a2 = wh[o*3+2];
        #pragma unroll
        for (int kb = 0; kb < 2; ++kb) {
            const float* wr = w1 + o * NUM_C + kb * 32 + lhi * 8;
            const float4 wa = *(const float4*)wr;
            const float4 wb = *(const float4*)(wr + 4);
            const float w8[8] = {wa.x,wa.y,wa.z,wa.w,wb.x,wb.y,wb.z,wb.w};
            #pragma unroll
            for (int i = 0; i < 8; ++i) {
                afrag[0][kb][i] = (short)bf16r(a0 * w8[i]);
                afrag[1][kb][i] = (short)bf16r(a1 * w8[i]);
                afrag[2][kb][i] = (short)bf16r(a2 * w8[i]);
            }
        }
    }

    if (tid < NUM_O) {
        wvb[tid][0] = wv[tid*3+0];
        wvb[tid][1] = wv[tid*3+1];
        wvb[tid][2] = wv[tid*3+2];
        wvb[tid][3] = bias[tid];
    }
    if (tid < XSS) {                   // zero pads of BOTH buffers (used when pack row invalid)
        xs0[0][tid] = 0; xs0[WT + 1][tid] = 0;
        xs1[0][tid] = 0; xs1[WT + 1][tid] = 0;
    }

    // main staging: thread owns wl = tid&127, c-chunk ch (16 channels); 16 coalesced dwords/row
    const int sw = tid & (WT - 1);
    const int ch = tid >> 7;           // [0,4)
    const float* xb = x + (size_t)b * NUM_C * DIM_H * DIM_W + w0 + sw;

    // halo staging: threads 0..127 own (c = tid&63, side = tid>>6) -> columns w0-1 / w0+WT
    const int  hc     = tid & 63;
    const int  hside  = (tid >> 6) & 1;
    const int  hwg    = w0 - 1 + hside * (WT + 1);
    const bool hvalid = (tid < 128) && (hwg >= 0) && (hwg < DIM_W);
    const float* hb   = x + ((size_t)(b * NUM_C + hc) * DIM_H) * DIM_W + hwg;

    float xr[16];
    float hx = 0.f;
    if (h0 > 0) {                      // prologue: loads for row h0-1 (packed at HH=-1)
        #pragma unroll
        for (int q = 0; q < 4; ++q)
            #pragma unroll
            for (int j = 0; j < 4; ++j)
                xr[q*4+j] = xb[(size_t)(ch*16+q*4+j)*(DIM_H*DIM_W) + (size_t)(h0-1)*DIM_W];
        if (hvalid) hx = hb[(size_t)(h0-1)*DIM_W];
    }

    f32x4 zP[4], zPP[4];               // z(hg-1), z(hg-2) per strip t
    #pragma unroll
    for (int t = 0; t < 4; ++t) { zP[t] = (f32x4){0,0,0,0}; zPP[t] = (f32x4){0,0,0,0}; }

    __syncthreads();

    // Iter HH: pack row hp=h0+HH -> XSP; issue loads row hp+1; GEMM row hg=hp-1 <- XSG;
    // store out row hg-1; ONE lgkm+barrier at iter end. Pack and GEMM overlap (disjoint buffers).
#define STEP(HH, XSP, XSG)                                                                \
    do {                                                                                  \
        const int  hp = h0 + (HH);                      /* row being packed   */          \
        const bool pv = (hp >= 0) && (hp < DIM_H);                                        \
        const int  hg = hp - 1;                         /* row being GEMMed   */          \
        const bool gv = ((HH) >= 0) && (hg >= 0) && (hg < DIM_H);                         \
        if (pv) {                                                                         \
            _Pragma("unroll")                                                             \
            for (int q = 0; q < 4; ++q) {                                                 \
                const unsigned lo = cvt_pk_bf16(xr[q*4+0], xr[q*4+1]);                    \
                const unsigned hi = cvt_pk_bf16(xr[q*4+2], xr[q*4+3]);                    \
                *(uint2*)&XSP[sw + 1][ch * 16 + q * 4] = make_uint2(lo, hi);              \
            }                                                                             \
            if (tid < 128)                                                                \
                XSP[hside * (WT + 1)][hc] = (unsigned short)(hvalid ? bf16r(hx) : 0u);    \
        }                                                                                 \
        if ((HH) + 1 <= SEG && hp + 1 < DIM_H) {        /* issue loads row hp+1 */        \
            _Pragma("unroll")                                                             \
            for (int q = 0; q < 4; ++q)                                                   \
                _Pragma("unroll")                                                         \
                for (int j = 0; j < 4; ++j)                                               \
                    xr[q*4+j] = xb[(size_t)(ch*16+q*4+j)*(DIM_H*DIM_W)                    \
                                   + (size_t)(hp+1)*DIM_W];                               \
            if (hvalid) hx = hb[(size_t)(hp+1)*DIM_W];                                    \
        }                                                                                 \
        {   /* GEMM row hg from XSG (ready since last barrier) + per-strip epilogue */    \
            const int cb = lhi * 8;                                                       \
            _Pragma("unroll")                                                             \
            for (int t = 0; t < 4; ++t) {                                                 \
                f32x4 acc = (f32x4){0.f,0.f,0.f,0.f};                                     \
                if (gv) {                                                                 \
                    const unsigned short* rp0 = &XSG[wq*64 + t*16 + l15][cb];             \
                    _Pragma("unroll")                                                     \
                    for (int s = 0; s < 3; ++s) {                                         \
                        const unsigned short* rp = rp0 + s * XSS;                         \
                        const bf16x8 b0 = *(const bf16x8*)rp;                             \
                        const bf16x8 b1 = *(const bf16x8*)(rp + 32);                      \
                        acc = __builtin_amdgcn_mfma_f32_16x16x32_bf16(afrag[s][0], b0, acc, 0,0,0); \
                        acc = __builtin_amdgcn_mfma_f32_16x16x32_bf16(afrag[s][1], b1, acc, 0,0,0); \
                    }                                                                     \
                }                                                                         \
                if ((HH) >= 2) {                        /* out row hg-1 complete */       \
                    _Pragma("unroll")                                                     \
                    for (int r = 0; r < 4; ++r) {                                         \
                        const int o = ot * 16 + lhi * 4 + r;                              \
                        const float4 cf = *(const float4*)wvb[o];                         \
                        out[((size_t)(b * NUM_O + o) * DIM_H + (hg - 1)) * DIM_W          \
                            + w0 + wq * 64 + t * 16 + l15] =                              \
                            cf.w + cf.x * zPP[t][r] + cf.y * zP[t][r] + cf.z * acc[r];    \
                    }                                                                     \
                }                                                                         \
                zPP[t] = zP[t]; zP[t] = acc;                                              \
            }                                                                             \
        }                                                                                 \
        asm volatile("s_waitcnt lgkmcnt(0)" ::: "memory");  /* pack visible */            \
        __builtin_amdgcn_s_barrier();                                                     \
    } while (0)

    STEP(-1, xs1, xs0);                // pack row h0-1 (GEMM skipped: HH<0)
    #pragma unroll
    for (int p = 0; p < (SEG + 2) / 2; ++p) {   // HH = 0..SEG+1; even->pack xs0, odd->pack xs1
        STEP(2 * p,     xs0, xs1);
        STEP(2 * p + 1, xs1, xs0);
    }
#undef STEP
}

extern "C" void kernel_launch(void* const* d_in, const int* in_sizes, int n_in,
                              void* d_out, int out_size, void* d_ws, size_t ws_size,
                              hipStream_t stream) {
    const float* x    = (const float*)d_in[0];
    const float* w1   = (const float*)d_in[1];
    const float* wh   = (const float*)d_in[2];
    const float* wv   = (const float*)d_in[3];
    const float* bias = (const float*)d_in[4];
    float* outp = (float*)d_out;
    cpd_mfma<<<dim3(NUM_B * 32 * 2), dim3(TPB), 0, stream>>>(x, w1, wh, wv, bias, outp);
}

// Round 10
// 63.533 us; speedup vs baseline: 5.8879x; 5.8879x over previous
//
#include <hip/hip_runtime.h>

#define NUM_B 8
#define NUM_C 64
#define NUM_O 64
#define DIM_H 256
#define DIM_W 256
#define SEG   8           // 8 output rows per block
#define WT    128         // w-tile per block -> grid 512
#define TPB   512
#define XSS   72          // xs row stride in bf16 elems: 144 B

typedef __attribute__((ext_vector_type(8))) short bf16x8;
typedef __attribute__((ext_vector_type(4))) float f32x4;

__device__ __forceinline__ unsigned bf16r(float f) {   // RTNE fp32 -> bf16 bits
    unsigned u = __float_as_uint(f);
    return (u + 0x7fffu + ((u >> 16) & 1u)) >> 16;
}
__device__ __forceinline__ unsigned cvt_pk_bf16(float lo, float hi) {
    unsigned r;
    asm("v_cvt_pk_bf16_f32 %0, %1, %2" : "=v"(r) : "v"(lo), "v"(hi));
    return r;
}

// launch_bounds(TPB, 2): the ONLY config observed to unlock >64 arch-VGPRs (R2: 96, no spill).
// (TPB,4) and waves_per_eu(4,4) both clamp to 64 VGPR and spill the prefetch banks
// (R5/R7/R8/R9: +128..+550 MB scratch traffic). Budget at min-2-waves/EU = 256 regs;
// live state ~54 VGPR + AGPR-side accumulators, so expect ~96-128 granted, zero spill.
__global__ __launch_bounds__(TPB, 2)
void cpd_mfma(const float* __restrict__ x, const float* __restrict__ w1,
              const float* __restrict__ wh, const float* __restrict__ wv,
              const float* __restrict__ bias, float* __restrict__ out)
{
    // one x-row slice, transposed: xs[wl+1][c] bf16; rows 0 and WT+1 hold halo (or zero at edges)
    __shared__ unsigned short xs[WT + 2][XSS];
    __shared__ float wvb[NUM_O][4];    // {wv0, wv1, wv2, bias} per o

    const int tid  = threadIdx.x;
    const int lane = tid & 63;
    const int wave = tid >> 6;         // [0,8)
    const int l15  = lane & 15;
    const int lhi  = lane >> 4;
    const int bx   = blockIdx.x;
    const int w0   = (bx & 1) * WT;
    const int h0   = ((bx >> 1) & 31) * SEG;
    const int b    = bx >> 6;

    const int ot = wave & 3;           // o-tile: o = ot*16 ..
    const int wq = wave >> 2;          // w-half of tile [0,2): wl = wq*64 ..

    // ---- A fragments (regs): A_s[o][c] = wh[o][s] * w1[o][c]; slot: m=o=l15, k=c=kb*32+lhi*8+i
    bf16x8 afrag[3][2];
    {
        const int o = ot * 16 + l15;
        const float a0 = wh[o*3+0], a1 = wh[o*3+1], a2 = wh[o*3+2];
        #pragma unroll
        for (int kb = 0; kb < 2; ++kb) {
            const float* wr = w1 + o * NUM_C + kb * 32 + lhi * 8;
            const float4 wa = *(const float4*)wr;
            const float4 wb = *(const float4*)(wr + 4);
            const float w8[8] = {wa.x,wa.y,wa.z,wa.w,wb.x,wb.y,wb.z,wb.w};
            #pragma unroll
            for (int i = 0; i < 8; ++i) {
                afrag[0][kb][i] = (short)bf16r(a0 * w8[i]);
                afrag[1][kb][i] = (short)bf16r(a1 * w8[i]);
                afrag[2][kb][i] = (short)bf16r(a2 * w8[i]);
            }
        }
    }

    if (tid < NUM_O) {
        wvb[tid][0] = wv[tid*3+0];
        wvb[tid][1] = wv[tid*3+1];
        wvb[tid][2] = wv[tid*3+2];
        wvb[tid][3] = bias[tid];
    }
    if (tid < XSS) { xs[0][tid] = 0; xs[WT + 1][tid] = 0; }

    // main staging: thread owns wl = tid&127, c-chunk ch (16 channels); 16 coalesced dwords/row
    const int sw = tid & (WT - 1);
    const int ch = tid >> 7;           // [0,4)
    const float* xb = x + (size_t)b * NUM_C * DIM_H * DIM_W + w0 + sw;

    // halo staging: threads 0..127 own (c = tid&63, side = tid>>6) -> columns w0-1 / w0+WT
    const int  hc     = tid & 63;
    const int  hside  = (tid >> 6) & 1;
    const int  hwg    = w0 - 1 + hside * (WT + 1);
    const bool hvalid = (tid < 128) && (hwg >= 0) && (hwg < DIM_W);
    const float* hb   = x + ((size_t)(b * NUM_C + hc) * DIM_H) * DIM_W + hwg;

    // depth-2 prefetch: two static row banks (A = odd hh, B = even hh)
    float xrA[16], xrB[16];
    float hxA = 0.f, hxB = 0.f;
    if (h0 > 0) {                      // bank A <- row h0-1
        #pragma unroll
        for (int q = 0; q < 4; ++q)
            #pragma unroll
            for (int j = 0; j < 4; ++j)
                xrA[q*4+j] = xb[(size_t)(ch*16+q*4+j)*(DIM_H*DIM_W) + (size_t)(h0-1)*DIM_W];
        if (hvalid) hxA = hb[(size_t)(h0-1)*DIM_W];
    }
    {                                  // bank B <- row h0 (always valid)
        #pragma unroll
        for (int q = 0; q < 4; ++q)
            #pragma unroll
            for (int j = 0; j < 4; ++j)
                xrB[q*4+j] = xb[(size_t)(ch*16+q*4+j)*(DIM_H*DIM_W) + (size_t)h0*DIM_W];
        if (hvalid) hxB = hb[(size_t)h0*DIM_W];
    }

    f32x4 zP[4], zPP[4];
    #pragma unroll
    for (int t = 0; t < 4; ++t) { zP[t] = (f32x4){0,0,0,0}; zPP[t] = (f32x4){0,0,0,0}; }

    __syncthreads();

    // one STEP = one x-row. Pack of bank P waits (register-tracked vmcnt) only on P's loads;
    // the other bank's 17 loads stay in flight across the whole step -> queue never drains.
#define STEP(HH, XR, HX)                                                                  \
    do {                                                                                  \
        const int  h  = h0 + (HH);                                                        \
        const bool hv = (h >= 0) && (h < DIM_H);                                          \
        __builtin_amdgcn_s_barrier();                   /* xs free */                     \
        __builtin_amdgcn_sched_barrier(0);                                                \
        if (hv) {                                                                         \
            _Pragma("unroll")                                                             \
            for (int q = 0; q < 4; ++q) {                                                 \
                const unsigned lo = cvt_pk_bf16(XR[q*4+0], XR[q*4+1]);                    \
                const unsigned hi = cvt_pk_bf16(XR[q*4+2], XR[q*4+3]);                    \
                *(uint2*)&xs[sw + 1][ch * 16 + q * 4] = make_uint2(lo, hi);               \
            }                                                                             \
            if (tid < 128)                                                                \
                xs[hside * (WT + 1)][hc] = (unsigned short)(hvalid ? bf16r(HX) : 0u);     \
        }                                                                                 \
        if ((HH) <= SEG - 2 && h + 2 < DIM_H) {         /* refill own bank: row h+2 */    \
            _Pragma("unroll")                                                             \
            for (int q = 0; q < 4; ++q)                                                   \
                _Pragma("unroll")                                                         \
                for (int j = 0; j < 4; ++j)                                               \
                    XR[q*4+j] = xb[(size_t)(ch*16+q*4+j)*(DIM_H*DIM_W)                    \
                                   + (size_t)(h+2)*DIM_W];                                \
            if (hvalid) HX = hb[(size_t)(h+2)*DIM_W];                                     \
        }                                                                                 \
        asm volatile("s_waitcnt lgkmcnt(0)" ::: "memory");                                \
        __builtin_amdgcn_s_barrier();                   /* xs ready (vmcnt in flight) */  \
        __builtin_amdgcn_sched_barrier(0);                                                \
        f32x4 acc[4];                                                                     \
        _Pragma("unroll")                                                                 \
        for (int t = 0; t < 4; ++t) acc[t] = (f32x4){0.f,0.f,0.f,0.f};                    \
        if (hv) {                                                                         \
            const int cb = lhi * 8;                                                       \
            _Pragma("unroll")                                                             \
            for (int t = 0; t < 4; ++t) {                                                 \
                const unsigned short* rp0 = &xs[wq*64 + t*16 + l15][cb];                  \
                _Pragma("unroll")                                                         \
                for (int s = 0; s < 3; ++s) {                                             \
                    const unsigned short* rp = rp0 + s * XSS;                             \
                    const bf16x8 b0 = *(const bf16x8*)rp;                                 \
                    const bf16x8 b1 = *(const bf16x8*)(rp + 32);                          \
                    acc[t] = __builtin_amdgcn_mfma_f32_16x16x32_bf16(afrag[s][0], b0, acc[t], 0,0,0); \
                    acc[t] = __builtin_amdgcn_mfma_f32_16x16x32_bf16(afrag[s][1], b1, acc[t], 0,0,0); \
                }                                                                         \
            }                                                                             \
        }                                                                                 \
        if ((HH) >= 1) {                                /* out row g = h-1 complete */    \
            const int g = h - 1;                                                          \
            _Pragma("unroll")                                                             \
            for (int r = 0; r < 4; ++r) {                                                 \
                const int o = ot * 16 + lhi * 4 + r;                                      \
                const float4 cf = *(const float4*)wvb[o];                                 \
                float* ob = out + ((size_t)(b * NUM_O + o) * DIM_H + g) * DIM_W           \
                                + w0 + wq * 64 + l15;                                     \
                _Pragma("unroll")                                                         \
                for (int t = 0; t < 4; ++t)                                               \
                    ob[t * 16] = cf.w + cf.x * zPP[t][r] + cf.y * zP[t][r]                \
                                      + cf.z * acc[t][r];                                 \
            }                                                                             \
        }                                                                                 \
        _Pragma("unroll")                                                                 \
        for (int t = 0; t < 4; ++t) { zPP[t] = zP[t]; zP[t] = acc[t]; }                   \
    } while (0)

    #pragma unroll
    for (int p = 0; p <= SEG / 2; ++p) {   // hh = -1..SEG; odd rows bank A, even rows bank B
        STEP(2 * p - 1, xrA, hxA);
        STEP(2 * p,     xrB, hxB);
    }
#undef STEP
}

extern "C" void kernel_launch(void* const* d_in, const int* in_sizes, int n_in,
                              void* d_out, int out_size, void* d_ws, size_t ws_size,
                              hipStream_t stream) {
    const float* x    = (const float*)d_in[0];
    const float* w1   = (const float*)d_in[1];
    const float* wh   = (const float*)d_in[2];
    const float* wv   = (const float*)d_in[3];
    const float* bias = (const float*)d_in[4];
    float* outp = (float*)d_out;
    cpd_mfma<<<dim3(NUM_B * 32 * 2), dim3(TPB), 0, stream>>>(x, w1, wh, wv, bias, outp);
}